// Round 7
// baseline (413.817 us; speedup 1.0000x reference)
//
#include <hip/hip_runtime.h>
#include <math.h>

// Problem constants
constexpr int B_ = 4;
constexpr int C_ = 192;
constexpr int N_ = 3136;
constexpr int K_ = 9;
constexpr int NG = N_ / 16;     // 196 row-groups of 16
constexpr int NSPLIT = 7;       // M splits
constexpr int SPLIT = 448;      // 448 = 4*112
constexpr int BM = 112;         // cols per m-tile (7 MFMA j-groups)
constexpr int NMT = 4;          // m-tiles per split, exact

typedef _Float16 half8 __attribute__((ext_vector_type(8)));
typedef float f32x4 __attribute__((ext_vector_type(4)));
typedef unsigned long long u64;
typedef unsigned int u32;

// ------- fused norm + transpose + f16 hi/lo split (MFMA-swizzled) -------
// Bit-exact norms: sequential c=0..191 sums over identical f32 values.
__global__ __launch_bounds__(256) void prep_fused(const float* __restrict__ src,
                                                  float* __restrict__ sq,
                                                  _Float16* __restrict__ hi_sw,
                                                  _Float16* __restrict__ lo_sw) {
  __shared__ float tile[C_ * 32];    // [c][n_loc], 24 KB
  __shared__ float inv_s[32];
  const int tid = threadIdx.x;
  const int n0 = blockIdx.x * 32, b = blockIdx.y;
  const float* sp = src + (size_t)b * C_ * N_ + n0;

  // phase 1: coalesced load of the 192x32 tile
  {
    int n_loc = tid & 31, cg = tid >> 5;     // 8 groups x 24 c's
#pragma unroll 6
    for (int i = 0; i < 24; ++i) {
      int c = cg * 24 + i;
      tile[c * 32 + n_loc] = sp[(size_t)c * N_ + n_loc];
    }
  }
  __syncthreads();

  // phase 2: exact sequential norms (32 threads; bank-conflict-free)
  if (tid < 32) {
    float s = 0.f;
#pragma unroll 16
    for (int c = 0; c < C_; ++c) { float v = tile[c * 32 + tid]; s += v * v; }
    float inv = 1.0f / fmaxf(sqrtf(s), 1e-12f);
    float s2 = 0.f;
#pragma unroll 16
    for (int c = 0; c < C_; ++c) { float v = tile[c * 32 + tid] * inv; s2 += v * v; }
    inv_s[tid] = inv;
    sq[b * N_ + n0 + tid] = s2;
  }
  __syncthreads();

  // phase 3: swizzled hi/lo writes; lane-linear 16B slots (coalesced 1KB/wave)
  if (tid < 128) {
    int h = tid >> 6, sl = tid & 63;
    int n_loc = h * 16 + (sl & 15), cq = sl >> 4;
    float inv = inv_s[n_loc];
    int g = (n0 >> 4) + h;
#pragma unroll
    for (int kc = 0; kc < 6; ++kc) {
      half8 hh, ll;
#pragma unroll
      for (int e = 0; e < 8; ++e) {
        float v = tile[(kc * 32 + cq * 8 + e) * 32 + n_loc] * inv;
        _Float16 hv = (fabsf(v) < 6.1035156e-5f) ? (_Float16)0.f : (_Float16)v;
        hh[e] = hv;
        ll[e] = (_Float16)((v - (float)hv) * 2048.0f);
      }
      size_t off = ((size_t)((b * NG + g) * 6 + kc) * 64 + sl) * 8;
      *(half8*)(hi_sw + off) = hh;
      *(half8*)(lo_sw + off) = ll;
    }
  }
}

// ---------------- fused split-f16 MFMA distance GEMM + exact branchless top-9 ----------------
__device__ __forceinline__ u32 fkey(float f) {
  u32 u = __float_as_uint(f);
  return u ^ (u32)(((int)u >> 31) | 0x80000000);
}

// exact u64 key packed as positive-finite f64 bits: [0][fkey 32][col 12][0 x19]
__device__ __forceinline__ double mkkey(u32 fk, u32 colsh19) {
  u64 kb = ((u64)(fk >> 1) << 32) | (u64)((fk << 31) | colsh19);
  return __longlong_as_double((long long)kb);
}

// branchless insert of v into ascending sorted K0..K8 (v_min_f64/v_max_f64)
#define INS9(v)                                                        \
  { K8 = fmax(K7, fmin(K8, v)); K7 = fmax(K6, fmin(K7, v));            \
    K6 = fmax(K5, fmin(K6, v)); K5 = fmax(K4, fmin(K5, v));            \
    K4 = fmax(K3, fmin(K4, v)); K3 = fmax(K2, fmin(K3, v));            \
    K2 = fmax(K1, fmin(K2, v)); K1 = fmax(K0, fmin(K1, v));            \
    K0 = fmin(K0, v); }

__device__ __forceinline__ u64 shflx(u64 v, int d) {
  int lo = __shfl_xor((int)(u32)(v & 0xffffffffull), d);
  int hi = __shfl_xor((int)(u32)(v >> 32), d);
  return ((u64)(u32)hi << 32) | (u32)lo;
}

#define SWPU(a, b) { u64 _l = (b < a) ? b : a; u64 _h = (b < a) ? a : b; a = _l; b = _h; }

#define MERGESTEP16U(dist)                                                     \
  { u64 o0  = shflx(J15, dist), o1  = shflx(J14, dist);                        \
    u64 o2  = shflx(J13, dist), o3  = shflx(J12, dist);                        \
    u64 o4  = shflx(J11, dist), o5  = shflx(J10, dist);                        \
    u64 o6  = shflx(J9, dist),  o7  = shflx(J8, dist);                         \
    u64 o8  = shflx(J7, dist),  o9  = shflx(J6, dist);                         \
    u64 o10 = shflx(J5, dist),  o11 = shflx(J4, dist);                         \
    u64 o12 = shflx(J3, dist),  o13 = shflx(J2, dist);                         \
    u64 o14 = shflx(J1, dist),  o15 = shflx(J0, dist);                         \
    J0 = J0 < o0 ? J0 : o0;     J1 = J1 < o1 ? J1 : o1;                        \
    J2 = J2 < o2 ? J2 : o2;     J3 = J3 < o3 ? J3 : o3;                        \
    J4 = J4 < o4 ? J4 : o4;     J5 = J5 < o5 ? J5 : o5;                        \
    J6 = J6 < o6 ? J6 : o6;     J7 = J7 < o7 ? J7 : o7;                        \
    J8 = J8 < o8 ? J8 : o8;     J9 = J9 < o9 ? J9 : o9;                        \
    J10 = J10 < o10 ? J10 : o10; J11 = J11 < o11 ? J11 : o11;                  \
    J12 = J12 < o12 ? J12 : o12; J13 = J13 < o13 ? J13 : o13;                  \
    J14 = J14 < o14 ? J14 : o14; J15 = J15 < o15 ? J15 : o15;                  \
    SWPU(J0, J8) SWPU(J1, J9) SWPU(J2, J10) SWPU(J3, J11)                      \
    SWPU(J4, J12) SWPU(J5, J13) SWPU(J6, J14) SWPU(J7, J15)                    \
    SWPU(J0, J4) SWPU(J1, J5) SWPU(J2, J6) SWPU(J3, J7)                        \
    SWPU(J8, J12) SWPU(J9, J13) SWPU(J10, J14) SWPU(J11, J15)                  \
    SWPU(J0, J2) SWPU(J1, J3) SWPU(J4, J6) SWPU(J5, J7)                        \
    SWPU(J8, J10) SWPU(J9, J11) SWPU(J12, J14) SWPU(J13, J15)                  \
    SWPU(J0, J1) SWPU(J2, J3) SWPU(J4, J5) SWPU(J6, J7)                        \
    SWPU(J8, J9) SWPU(J10, J11) SWPU(J12, J13) SWPU(J14, J15) }

// block=256, 5 blocks/CU: LDS 30KB*5=153.6KB<160KB; VGPR cap 102 (kernel uses 84).
// R6's (256,3) capped occupancy at 29.7% and was the binding stall constraint.
__global__ __launch_bounds__(256, 5) void gemm_topk(
    const _Float16* __restrict__ xh, const _Float16* __restrict__ xl,
    const _Float16* __restrict__ yh, const _Float16* __restrict__ yl,
    const float* __restrict__ rp, const float* __restrict__ x2a,
    const float* __restrict__ y2a, u64* __restrict__ cand) {
  __shared__ __align__(16) _Float16 Bs[2 * 7168];      // 7 groups x (hi,lo) x 512, dbuf
  __shared__ __align__(16) float y2s[SPLIT];           // split's y2 segment

  const int tid = threadIdx.x, w = tid >> 6, l = tid & 63;
  const int b = blockIdx.z, s = blockIdx.y, n0 = blockIdx.x * 64;

  // ---- y2 split-segment into LDS (first use is after >=6 barriers) ----
  if (tid < SPLIT / 4)
    *(f32x4*)(y2s + tid * 4) = *(const f32x4*)(y2a + b * N_ + s * SPLIT + tid * 4);

  // ---- X (rows) resident in registers: hi + scaled-lo, 6 k-chunks ----
  half8 Xh[6], Xl[6];
  {
    size_t base = (size_t)((b * NG + (n0 >> 4) + w) * 6) * 512 + (size_t)l * 8;
#pragma unroll
    for (int kc = 0; kc < 6; ++kc) {
      Xh[kc] = *(const half8*)(xh + base + kc * 512);
      Xl[kc] = *(const half8*)(xl + base + kc * 512);
    }
  }

  auto stageB = [&](int mt, int kc, int bufn) {
    int gb = s * 28 + mt * 7;        // (s*SPLIT + mt*BM)/16
#pragma unroll
    for (int i = 0; i < 4; ++i) {
      int idx = tid + i * 256;       // 896 half8 chunks total
      if (idx < 896) {
        int g = idx >> 7, rem = idx & 127, h = rem >> 6, sl = rem & 63;
        const _Float16* srcp = h ? yl : yh;
        *(half8*)(Bs + bufn * 7168 + (g * 2 + h) * 512 + sl * 8) =
            *(const half8*)(srcp + (size_t)((b * NG + gb + g) * 6 + kc) * 512 + sl * 8);
      }
    }
  };
  stageB(0, 0, 0);

  // exact per-lane streaming top-9 as f64-packed keys
  double K0, K1, K2, K3, K4, K5, K6, K7, K8;
  K0 = K1 = K2 = K3 = K4 = K5 = K6 = K7 = K8 =
      __longlong_as_double(0x7FF0000000000000LL);  // +Inf sentinel

  // swapped-operand C layout: lane owns x-row = l&15, y-cols = (l>>4)*4 + e
  const int row_l = l & 15;
  const int cq = (l >> 4) * 4;
  const int n_glob = n0 + w * 16 + row_l;
  const float x2v = x2a[b * N_ + n_glob];
  const float* rpn = rp + (size_t)n_glob * N_ + s * SPLIT;

  int buf = 0;
  for (int mt = 0; mt < NMT; ++mt) {
    f32x4 acc1[7], acc2[7];
#pragma unroll
    for (int j = 0; j < 7; ++j) {
      acc1[j] = (f32x4){0.f, 0.f, 0.f, 0.f};
      acc2[j] = (f32x4){0.f, 0.f, 0.f, 0.f};
    }

    // prefetch this tile's rp (consumed in epilogue; latency covered by kc loop)
    f32x4 rpv[7];
#pragma unroll
    for (int j = 0; j < 7; ++j)
      rpv[j] = *(const f32x4*)(rpn + mt * BM + j * 16 + cq);

    for (int kc = 0; kc < 6; ++kc) {
      __syncthreads();
      if (kc < 5) stageB(mt, kc + 1, buf ^ 1);
      else if (mt + 1 < NMT) stageB(mt + 1, 0, buf ^ 1);
      half8 ah = Xh[kc], al = Xl[kc];
#pragma unroll
      for (int j = 0; j < 7; ++j) {
        half8 bh = *(const half8*)(Bs + buf * 7168 + (j * 2) * 512 + l * 8);
        half8 bl = *(const half8*)(Bs + buf * 7168 + (j * 2 + 1) * 512 + l * 8);
        // D[col][row]: first operand (y) -> C-row dim, second (x) -> C-col dim
        acc2[j] = __builtin_amdgcn_mfma_f32_16x16x32_f16(bh, al, acc2[j], 0, 0, 0);
        acc2[j] = __builtin_amdgcn_mfma_f32_16x16x32_f16(bl, ah, acc2[j], 0, 0, 0);
        acc1[j] = __builtin_amdgcn_mfma_f32_16x16x32_f16(bh, ah, acc1[j], 0, 0, 0);
      }
      buf ^= 1;
    }

    // ---- epilogue: all inputs in regs/LDS; branchless exact top-9 ----
#pragma unroll
    for (int j = 0; j < 7; ++j) {
      const int cl = mt * BM + j * 16 + cq;     // local col in split
      const int colg = s * SPLIT + cl;          // global col
      f32x4 y2v = *(const f32x4*)(y2s + cl);
      const u32 csh = (u32)colg << 19;
#pragma unroll
      for (int e = 0; e < 4; ++e) {
        float dot = acc1[j][e] + acc2[j][e] * (1.0f / 2048.0f);
        float ss = fmaxf(__builtin_fmaf(-2.0f, dot, x2v + y2v[e]), 0.0f);
        float d = __builtin_amdgcn_sqrtf(ss) + rpv[j][e];
        double ck = mkkey(fkey(d), csh + ((u32)e << 19));
        INS9(ck)
      }
    }
  }

  // ---- cross-lane merge: 4 scan-lanes per row (xor 16,32) -> row/split top-9 ----
  {
    u64 J0 = (u64)__double_as_longlong(K0), J1 = (u64)__double_as_longlong(K1),
        J2 = (u64)__double_as_longlong(K2), J3 = (u64)__double_as_longlong(K3),
        J4 = (u64)__double_as_longlong(K4), J5 = (u64)__double_as_longlong(K5),
        J6 = (u64)__double_as_longlong(K6), J7 = (u64)__double_as_longlong(K7),
        J8 = (u64)__double_as_longlong(K8);
    u64 J9 = 0x7FF0000000000000ull, J10 = J9, J11 = J9, J12 = J9, J13 = J9,
        J14 = J9, J15 = J9;
    MERGESTEP16U(16)
    MERGESTEP16U(32)
    if (l < 16) {
      u64* o = cand + ((size_t)(b * N_ + n_glob) * NSPLIT + s) * 9;
      o[0] = J0; o[1] = J1; o[2] = J2; o[3] = J3; o[4] = J4;
      o[5] = J5; o[6] = J6; o[7] = J7; o[8] = J8;
    }
  }
}

// ---------------- merge: wave per row, 63 exact keys -> top-9 ----------------
__device__ __forceinline__ double shflx_f64(double v, int d) {
  u64 bb = (u64)__double_as_longlong(v);
  int lo = __shfl_xor((int)(u32)bb, d);
  int hi = __shfl_xor((int)(bb >> 32), d);
  return __longlong_as_double(((long long)(u32)hi << 32) | (u32)lo);
}

__global__ __launch_bounds__(256) void merge_kernel(const u64* __restrict__ cand,
                                                    int* __restrict__ out) {
  const int l = threadIdx.x & 63;
  const int r = blockIdx.x * 4 + (threadIdx.x >> 6);   // row id, 12544 total
  const int n = r % N_;
  const double INF = __longlong_as_double(0x7FF0000000000000LL);
  double v = (l < NSPLIT * 9) ? __longlong_as_double((long long)cand[(size_t)r * (NSPLIT * 9) + l])
                              : INF;
  const int ob = r * K_;
#pragma unroll
  for (int k = 0; k < K_; ++k) {
    double m = v;
    m = fmin(m, shflx_f64(m, 1));
    m = fmin(m, shflx_f64(m, 2));
    m = fmin(m, shflx_f64(m, 4));
    m = fmin(m, shflx_f64(m, 8));
    m = fmin(m, shflx_f64(m, 16));
    m = fmin(m, shflx_f64(m, 32));
    if (v == m) v = INF;        // keys unique (distinct cols)
    if (l == 0) {
      u64 mb = (u64)__double_as_longlong(m);
      out[ob + k] = (int)((mb >> 19) & 0xFFFu);
      out[B_ * N_ * K_ + ob + k] = n;
    }
  }
}

extern "C" void kernel_launch(void* const* d_in, const int* in_sizes, int n_in,
                              void* d_out, int out_size, void* d_ws, size_t ws_size,
                              hipStream_t stream) {
  const float* x = (const float*)d_in[0];
  const float* y = (const float*)d_in[1];
  const float* rp = (const float*)d_in[2];
  int* out = (int*)d_out;

  char* ws = (char*)d_ws;
  size_t off = 0;
  auto alloc = [&](size_t bytes) { char* p = ws + off; off += (bytes + 255) & ~(size_t)255; return p; };
  float* x2 = (float*)alloc(B_ * N_ * 4);
  float* y2 = (float*)alloc(B_ * N_ * 4);
  _Float16* xh = (_Float16*)alloc((size_t)B_ * N_ * C_ * 2);
  _Float16* xl = (_Float16*)alloc((size_t)B_ * N_ * C_ * 2);
  _Float16* yh = (_Float16*)alloc((size_t)B_ * N_ * C_ * 2);
  _Float16* yl = (_Float16*)alloc((size_t)B_ * N_ * C_ * 2);
  u64* cand = (u64*)alloc((size_t)B_ * N_ * NSPLIT * 9 * 8);

  prep_fused<<<dim3(N_ / 32, B_), 256, 0, stream>>>(x, x2, xh, xl);
  prep_fused<<<dim3(N_ / 32, B_), 256, 0, stream>>>(y, y2, yh, yl);
  gemm_topk<<<dim3(N_ / 64, NSPLIT, B_), 256, 0, stream>>>(xh, xl, yh, yl, rp, x2, y2, cand);
  merge_kernel<<<B_ * N_ / 4, 256, 0, stream>>>(cand, out);
}

// Round 9
// 236.899 us; speedup vs baseline: 1.7468x; 1.7468x over previous
//
#include <hip/hip_runtime.h>
#include <math.h>

// Problem constants
constexpr int B_ = 4;
constexpr int C_ = 192;
constexpr int N_ = 3136;
constexpr int K_ = 9;
constexpr int NG = N_ / 16;     // 196 row-groups of 16
constexpr int NSPLIT = 7;       // M splits
constexpr int SPLIT = 448;      // 448 = 4*112
constexpr int BM = 112;         // cols per m-tile (7 MFMA j-groups)
constexpr int NMT = 4;          // m-tiles per split, exact
constexpr int NROWS = B_ * N_;  // 12544

typedef _Float16 half8 __attribute__((ext_vector_type(8)));
typedef float f32x4 __attribute__((ext_vector_type(4)));
typedef unsigned long long u64;
typedef unsigned int u32;

// ------- fused norm + transpose + f16 hi/lo split (MFMA-swizzled) -------
// One dispatch covers BOTH inputs (blockIdx.z selects x/y). Body identical to
// the proven R6 prep (bit-identical outputs).
__global__ __launch_bounds__(256) void prep_fused(
    const float* __restrict__ xsrc, const float* __restrict__ ysrc,
    float* __restrict__ sqx, float* __restrict__ sqy,
    _Float16* __restrict__ xh, _Float16* __restrict__ xl,
    _Float16* __restrict__ yh, _Float16* __restrict__ yl) {
  __shared__ float tile[C_ * 32];    // [c][n_loc], 24 KB
  __shared__ float inv_s[32];
  const int tid = threadIdx.x;
  const int n0 = blockIdx.x * 32, b = blockIdx.y, which = blockIdx.z;
  const float* src = which ? ysrc : xsrc;
  float* sq = which ? sqy : sqx;
  _Float16* hi_sw = which ? yh : xh;
  _Float16* lo_sw = which ? yl : xl;
  const float* sp = src + (size_t)b * C_ * N_ + n0;

  // phase 1: coalesced load of the 192x32 tile
  {
    int n_loc = tid & 31, cg = tid >> 5;     // 8 groups x 24 c's
#pragma unroll 6
    for (int i = 0; i < 24; ++i) {
      int c = cg * 24 + i;
      tile[c * 32 + n_loc] = sp[(size_t)c * N_ + n_loc];
    }
  }
  __syncthreads();

  // phase 2: exact sequential norms (32 threads; bank-conflict-free)
  if (tid < 32) {
    float s = 0.f;
#pragma unroll 16
    for (int c = 0; c < C_; ++c) { float v = tile[c * 32 + tid]; s += v * v; }
    float inv = 1.0f / fmaxf(sqrtf(s), 1e-12f);
    float s2 = 0.f;
#pragma unroll 16
    for (int c = 0; c < C_; ++c) { float v = tile[c * 32 + tid] * inv; s2 += v * v; }
    inv_s[tid] = inv;
    sq[b * N_ + n0 + tid] = s2;
  }
  __syncthreads();

  // phase 3: swizzled hi/lo writes; lane-linear 16B slots (coalesced 1KB/wave)
  if (tid < 128) {
    int h = tid >> 6, sl = tid & 63;
    int n_loc = h * 16 + (sl & 15), cq = sl >> 4;
    float inv = inv_s[n_loc];
    int g = (n0 >> 4) + h;
#pragma unroll
    for (int kc = 0; kc < 6; ++kc) {
      half8 hh, ll;
#pragma unroll
      for (int e = 0; e < 8; ++e) {
        float v = tile[(kc * 32 + cq * 8 + e) * 32 + n_loc] * inv;
        _Float16 hv = (fabsf(v) < 6.1035156e-5f) ? (_Float16)0.f : (_Float16)v;
        hh[e] = hv;
        ll[e] = (_Float16)((v - (float)hv) * 2048.0f);
      }
      size_t off = ((size_t)((b * NG + g) * 6 + kc) * 64 + sl) * 8;
      *(half8*)(hi_sw + off) = hh;
      *(half8*)(lo_sw + off) = ll;
    }
  }
}

// ---------------- fused split-f16 MFMA distance GEMM + exact branchless top-9 ----------------
__device__ __forceinline__ u32 fkey(float f) {
  u32 u = __float_as_uint(f);
  return u ^ (u32)(((int)u >> 31) | 0x80000000);
}

// exact u64 key packed as positive-finite f64 bits: [0][fkey 32][col 12][0 x19]
__device__ __forceinline__ double mkkey(u32 fk, u32 colsh19) {
  u64 kb = ((u64)(fk >> 1) << 32) | (u64)((fk << 31) | colsh19);
  return __longlong_as_double((long long)kb);
}

// branchless insert of v into ascending sorted K0..K8 (v_min_f64/v_max_f64)
#define INS9(v)                                                        \
  { K8 = fmax(K7, fmin(K8, v)); K7 = fmax(K6, fmin(K7, v));            \
    K6 = fmax(K5, fmin(K6, v)); K5 = fmax(K4, fmin(K5, v));            \
    K4 = fmax(K3, fmin(K4, v)); K3 = fmax(K2, fmin(K3, v));            \
    K2 = fmax(K1, fmin(K2, v)); K1 = fmax(K0, fmin(K1, v));            \
    K0 = fmin(K0, v); }

__device__ __forceinline__ u64 shflx(u64 v, int d) {
  int lo = __shfl_xor((int)(u32)(v & 0xffffffffull), d);
  int hi = __shfl_xor((int)(u32)(v >> 32), d);
  return ((u64)(u32)hi << 32) | (u32)lo;
}

#define SWPU(a, b) { u64 _l = (b < a) ? b : a; u64 _h = (b < a) ? a : b; a = _l; b = _h; }

#define MERGESTEP16U(dist)                                                     \
  { u64 o0  = shflx(J15, dist), o1  = shflx(J14, dist);                        \
    u64 o2  = shflx(J13, dist), o3  = shflx(J12, dist);                        \
    u64 o4  = shflx(J11, dist), o5  = shflx(J10, dist);                        \
    u64 o6  = shflx(J9, dist),  o7  = shflx(J8, dist);                         \
    u64 o8  = shflx(J7, dist),  o9  = shflx(J6, dist);                         \
    u64 o10 = shflx(J5, dist),  o11 = shflx(J4, dist);                         \
    u64 o12 = shflx(J3, dist),  o13 = shflx(J2, dist);                         \
    u64 o14 = shflx(J1, dist),  o15 = shflx(J0, dist);                         \
    J0 = J0 < o0 ? J0 : o0;     J1 = J1 < o1 ? J1 : o1;                        \
    J2 = J2 < o2 ? J2 : o2;     J3 = J3 < o3 ? J3 : o3;                        \
    J4 = J4 < o4 ? J4 : o4;     J5 = J5 < o5 ? J5 : o5;                        \
    J6 = J6 < o6 ? J6 : o6;     J7 = J7 < o7 ? J7 : o7;                        \
    J8 = J8 < o8 ? J8 : o8;     J9 = J9 < o9 ? J9 : o9;                        \
    J10 = J10 < o10 ? J10 : o10; J11 = J11 < o11 ? J11 : o11;                  \
    J12 = J12 < o12 ? J12 : o12; J13 = J13 < o13 ? J13 : o13;                  \
    J14 = J14 < o14 ? J14 : o14; J15 = J15 < o15 ? J15 : o15;                  \
    SWPU(J0, J8) SWPU(J1, J9) SWPU(J2, J10) SWPU(J3, J11)                      \
    SWPU(J4, J12) SWPU(J5, J13) SWPU(J6, J14) SWPU(J7, J15)                    \
    SWPU(J0, J4) SWPU(J1, J5) SWPU(J2, J6) SWPU(J3, J7)                        \
    SWPU(J8, J12) SWPU(J9, J13) SWPU(J10, J14) SWPU(J11, J15)                  \
    SWPU(J0, J2) SWPU(J1, J3) SWPU(J4, J6) SWPU(J5, J7)                        \
    SWPU(J8, J10) SWPU(J9, J11) SWPU(J12, J14) SWPU(J13, J15)                  \
    SWPU(J0, J1) SWPU(J2, J3) SWPU(J4, J5) SWPU(J6, J7)                        \
    SWPU(J8, J9) SWPU(J10, J11) SWPU(J12, J13) SWPU(J14, J15) }

// block=256, 3 blocks/CU. R7 post-mortem: (256,5) caps unified VGPR+AGPR at
// ~96 < the ~140 needed -> accumulator spill, 865 MB scratch, 2.1x slower.
// R8 post-mortem: global_load_lds via integer-truncated LDS pointer faults;
// occupancy here is register-pinned. This is the proven R6 kernel; only the
// cand write layout changed (transposed for the cheap merge).
__global__ __launch_bounds__(256, 3) void gemm_topk(
    const _Float16* __restrict__ xh, const _Float16* __restrict__ xl,
    const _Float16* __restrict__ yh, const _Float16* __restrict__ yl,
    const float* __restrict__ rp, const float* __restrict__ x2a,
    const float* __restrict__ y2a, u64* __restrict__ cand) {
  __shared__ __align__(16) _Float16 Bs[2 * 7168];      // 7 groups x (hi,lo) x 512, dbuf
  __shared__ __align__(16) float y2s[SPLIT];           // split's y2 segment

  const int tid = threadIdx.x, w = tid >> 6, l = tid & 63;
  const int b = blockIdx.z, s = blockIdx.y, n0 = blockIdx.x * 64;

  // ---- y2 split-segment into LDS (first use is after >=6 barriers) ----
  if (tid < SPLIT / 4)
    *(f32x4*)(y2s + tid * 4) = *(const f32x4*)(y2a + b * N_ + s * SPLIT + tid * 4);

  // ---- X (rows) resident in registers: hi + scaled-lo, 6 k-chunks ----
  half8 Xh[6], Xl[6];
  {
    size_t base = (size_t)((b * NG + (n0 >> 4) + w) * 6) * 512 + (size_t)l * 8;
#pragma unroll
    for (int kc = 0; kc < 6; ++kc) {
      Xh[kc] = *(const half8*)(xh + base + kc * 512);
      Xl[kc] = *(const half8*)(xl + base + kc * 512);
    }
  }

  auto stageB = [&](int mt, int kc, int bufn) {
    int gb = s * 28 + mt * 7;        // (s*SPLIT + mt*BM)/16
#pragma unroll
    for (int i = 0; i < 4; ++i) {
      int idx = tid + i * 256;       // 896 half8 chunks total
      if (idx < 896) {
        int g = idx >> 7, rem = idx & 127, h = rem >> 6, sl = rem & 63;
        const _Float16* srcp = h ? yl : yh;
        *(half8*)(Bs + bufn * 7168 + (g * 2 + h) * 512 + sl * 8) =
            *(const half8*)(srcp + (size_t)((b * NG + gb + g) * 6 + kc) * 512 + sl * 8);
      }
    }
  };
  stageB(0, 0, 0);

  // exact per-lane streaming top-9 as f64-packed keys
  double K0, K1, K2, K3, K4, K5, K6, K7, K8;
  K0 = K1 = K2 = K3 = K4 = K5 = K6 = K7 = K8 =
      __longlong_as_double(0x7FF0000000000000LL);  // +Inf sentinel

  // swapped-operand C layout: lane owns x-row = l&15, y-cols = (l>>4)*4 + e
  const int row_l = l & 15;
  const int cq = (l >> 4) * 4;
  const int n_glob = n0 + w * 16 + row_l;
  const float x2v = x2a[b * N_ + n_glob];
  const float* rpn = rp + (size_t)n_glob * N_ + s * SPLIT;

  int buf = 0;
  for (int mt = 0; mt < NMT; ++mt) {
    f32x4 acc1[7], acc2[7];
#pragma unroll
    for (int j = 0; j < 7; ++j) {
      acc1[j] = (f32x4){0.f, 0.f, 0.f, 0.f};
      acc2[j] = (f32x4){0.f, 0.f, 0.f, 0.f};
    }

    // prefetch this tile's rp (consumed in epilogue; latency covered by kc loop)
    f32x4 rpv[7];
#pragma unroll
    for (int j = 0; j < 7; ++j)
      rpv[j] = *(const f32x4*)(rpn + mt * BM + j * 16 + cq);

    for (int kc = 0; kc < 6; ++kc) {
      __syncthreads();
      if (kc < 5) stageB(mt, kc + 1, buf ^ 1);
      else if (mt + 1 < NMT) stageB(mt + 1, 0, buf ^ 1);
      half8 ah = Xh[kc], al = Xl[kc];
#pragma unroll
      for (int j = 0; j < 7; ++j) {
        half8 bh = *(const half8*)(Bs + buf * 7168 + (j * 2) * 512 + l * 8);
        half8 bl = *(const half8*)(Bs + buf * 7168 + (j * 2 + 1) * 512 + l * 8);
        // D[col][row]: first operand (y) -> C-row dim, second (x) -> C-col dim
        acc2[j] = __builtin_amdgcn_mfma_f32_16x16x32_f16(bh, al, acc2[j], 0, 0, 0);
        acc2[j] = __builtin_amdgcn_mfma_f32_16x16x32_f16(bl, ah, acc2[j], 0, 0, 0);
        acc1[j] = __builtin_amdgcn_mfma_f32_16x16x32_f16(bh, ah, acc1[j], 0, 0, 0);
      }
      buf ^= 1;
    }

    // ---- epilogue: all inputs in regs/LDS; branchless exact top-9 ----
#pragma unroll
    for (int j = 0; j < 7; ++j) {
      const int cl = mt * BM + j * 16 + cq;     // local col in split
      const int colg = s * SPLIT + cl;          // global col
      f32x4 y2v = *(const f32x4*)(y2s + cl);
      const u32 csh = (u32)colg << 19;
#pragma unroll
      for (int e = 0; e < 4; ++e) {
        float dot = acc1[j][e] + acc2[j][e] * (1.0f / 2048.0f);
        float ss = fmaxf(__builtin_fmaf(-2.0f, dot, x2v + y2v[e]), 0.0f);
        float d = __builtin_amdgcn_sqrtf(ss) + rpv[j][e];
        double ck = mkkey(fkey(d), csh + ((u32)e << 19));
        INS9(ck)
      }
    }
  }

  // ---- cross-lane merge: 4 scan-lanes per row (xor 16,32) -> row/split top-9 ----
  // cand layout TRANSPOSED: plane (s*9+k) of NROWS u64 -> coalesced merge reads.
  {
    u64 J0 = (u64)__double_as_longlong(K0), J1 = (u64)__double_as_longlong(K1),
        J2 = (u64)__double_as_longlong(K2), J3 = (u64)__double_as_longlong(K3),
        J4 = (u64)__double_as_longlong(K4), J5 = (u64)__double_as_longlong(K5),
        J6 = (u64)__double_as_longlong(K6), J7 = (u64)__double_as_longlong(K7),
        J8 = (u64)__double_as_longlong(K8);
    u64 J9 = 0x7FF0000000000000ull, J10 = J9, J11 = J9, J12 = J9, J13 = J9,
        J14 = J9, J15 = J9;
    MERGESTEP16U(16)
    MERGESTEP16U(32)
    if (l < 16) {
      u64* o = cand + (size_t)(s * 9) * NROWS + (size_t)b * N_ + n_glob;
      o[0 * NROWS] = J0; o[1 * NROWS] = J1; o[2 * NROWS] = J2;
      o[3 * NROWS] = J3; o[4 * NROWS] = J4; o[5 * NROWS] = J5;
      o[6 * NROWS] = J6; o[7 * NROWS] = J7; o[8 * NROWS] = J8;
    }
  }
}

// ---------------- merge: thread per row, 63 exact keys -> top-9 ----------------
// Coalesced plane-major reads; branchless f64 INS9 (no shuffles, no LDS).
__global__ __launch_bounds__(256) void merge_kernel(const u64* __restrict__ cand,
                                                    int* __restrict__ out) {
  const int r = blockIdx.x * 256 + threadIdx.x;   // row id, 12544 total (exact)
  const int n = r % N_;
  double K0, K1, K2, K3, K4, K5, K6, K7, K8;
  K0 = K1 = K2 = K3 = K4 = K5 = K6 = K7 = K8 =
      __longlong_as_double(0x7FF0000000000000LL);
#pragma unroll 9
  for (int i = 0; i < NSPLIT * 9; ++i) {
    double ck = __longlong_as_double((long long)cand[(size_t)i * NROWS + r]);
    INS9(ck)
  }
  const int ob = r * K_;
  u64 kk[9] = {(u64)__double_as_longlong(K0), (u64)__double_as_longlong(K1),
               (u64)__double_as_longlong(K2), (u64)__double_as_longlong(K3),
               (u64)__double_as_longlong(K4), (u64)__double_as_longlong(K5),
               (u64)__double_as_longlong(K6), (u64)__double_as_longlong(K7),
               (u64)__double_as_longlong(K8)};
#pragma unroll
  for (int k = 0; k < K_; ++k) out[ob + k] = (int)((kk[k] >> 19) & 0xFFFu);
  int* oc = out + B_ * N_ * K_ + ob;
#pragma unroll
  for (int k = 0; k < K_; ++k) oc[k] = n;
}

extern "C" void kernel_launch(void* const* d_in, const int* in_sizes, int n_in,
                              void* d_out, int out_size, void* d_ws, size_t ws_size,
                              hipStream_t stream) {
  const float* x = (const float*)d_in[0];
  const float* y = (const float*)d_in[1];
  const float* rp = (const float*)d_in[2];
  int* out = (int*)d_out;

  char* ws = (char*)d_ws;
  size_t off = 0;
  auto alloc = [&](size_t bytes) { char* p = ws + off; off += (bytes + 255) & ~(size_t)255; return p; };
  float* x2 = (float*)alloc(B_ * N_ * 4);
  float* y2 = (float*)alloc(B_ * N_ * 4);
  _Float16* xh = (_Float16*)alloc((size_t)B_ * N_ * C_ * 2);
  _Float16* xl = (_Float16*)alloc((size_t)B_ * N_ * C_ * 2);
  _Float16* yh = (_Float16*)alloc((size_t)B_ * N_ * C_ * 2);
  _Float16* yl = (_Float16*)alloc((size_t)B_ * N_ * C_ * 2);
  u64* cand = (u64*)alloc((size_t)NSPLIT * 9 * NROWS * 8);

  prep_fused<<<dim3(N_ / 32, B_, 2), 256, 0, stream>>>(x, y, x2, y2, xh, xl, yh, yl);
  gemm_topk<<<dim3(N_ / 64, NSPLIT, B_), 256, 0, stream>>>(xh, xl, yh, yl, rp, x2, y2, cand);
  merge_kernel<<<NROWS / 256, 256, 0, stream>>>(cand, out);
}